// Round 8
// baseline (221.075 us; speedup 1.0000x reference)
//
#include <hip/hip_runtime.h>

// ---------------------------------------------------------------------------
// ModernBertAttention: x[4,2048,768] -> QKV gemm(+RoPE) -> sliding-window
// MFMA attention (window=64) -> out-proj gemm.  out f32 [4,2048,768].
// ---------------------------------------------------------------------------

typedef __attribute__((ext_vector_type(8))) _Float16 f16x8;
typedef __attribute__((ext_vector_type(4))) float    f32x4;

#define BDIM 4
#define SDIM 2048
#define HDIM 768
#define NH   12
#define HD   64
#define NQKV 2304   // 3*HDIM
#define MROWS 8192  // B*S

// --------------------------- f32 -> f16 convert ----------------------------
__global__ __launch_bounds__(256) void cvt_f32_f16(
    const float* __restrict__ src, _Float16* __restrict__ dst, int n8)
{
    int i = blockIdx.x * 256 + threadIdx.x;
    if (i >= n8) return;
    const float4* s4 = (const float4*)src + (long)i * 2;
    float4 a = s4[0], b = s4[1];
    f16x8 o;
    o[0] = (_Float16)a.x; o[1] = (_Float16)a.y;
    o[2] = (_Float16)a.z; o[3] = (_Float16)a.w;
    o[4] = (_Float16)b.x; o[5] = (_Float16)b.y;
    o[6] = (_Float16)b.z; o[7] = (_Float16)b.w;
    *((f16x8*)dst + i) = o;
}

// ------------------------ direct-global GEMM --------------------------------
// C[M,N] = A[M,K]*Bt[N,K]^T, fp16 in, fp32 acc. NO LDS, NO barriers.
// Rationale: B is a weight matrix (<=3.5MB, L2-resident per XCD) and K=768 is
// small; every prior LDS-staged schedule was barrier/latency-bound at 15%
// MfmaUtil with 1-2 blocks/CU. Here each wave reads its MFMA fragments
// directly from global (L1/L2-served, 64B contiguous per row per instr;
// adjacent k-step consumes the other half of each 128B line), hand-pipelined
// 2-deep in registers. Occupancy is VGPR-bound (~12 waves/CU), and with no
// barriers the compiler is free to hoist loads across MFMA clusters.
// Tile 128x128, 4 waves (2x2), wave tile 64x64.
// EPI==0: plain f32 C store.
// EPI==1: RoPE on q/k + scatter q/k/v (f16) to [B,nh,S,hd].
template <int EPI>
__global__ __launch_bounds__(256) void gemm_direct(
    const _Float16* __restrict__ A,
    const _Float16* __restrict__ Bt,
    float* __restrict__ C,
    const float* __restrict__ cosp,
    const float* __restrict__ sinp,
    _Float16* __restrict__ qh,
    _Float16* __restrict__ kh,
    _Float16* __restrict__ vh,
    int M, int N, int K)
{
    int nTn = N >> 7;
    int nwg = gridDim.x;
    int bid = blockIdx.x;
    int cpx = nwg >> 3;                       // grids are %8==0
    int wg  = (bid & 7) * cpx + (bid >> 3);   // XCD-aware bijective swizzle
    int tm = wg / nTn, tn = wg % nTn;
    int m0 = tm << 7, n0 = tn << 7;

    int tid  = threadIdx.x;
    int lane = tid & 63;
    int w    = tid >> 6;
    int wr   = w >> 1, wc = w & 1;
    int l15  = lane & 15, lk = lane >> 4;

    // per-fragment global base pointers (A-operand layout: row=l15, k=lk*8+e)
    const _Float16* pa[4];
    const _Float16* pb[4];
#pragma unroll
    for (int mf = 0; mf < 4; ++mf)
        pa[mf] = A + (long)(m0 + wr * 64 + mf * 16 + l15) * K + lk * 8;
#pragma unroll
    for (int nf = 0; nf < 4; ++nf)
        pb[nf] = Bt + (long)(n0 + wc * 64 + nf * 16 + l15) * K + lk * 8;

    f32x4 acc[4][4] = {};
    f16x8 a0[4], b0[4], a1[4], b1[4];

#define LD(av, bv, kk) do {                                              \
        _Pragma("unroll")                                                \
        for (int i = 0; i < 4; ++i) av[i] = *(const f16x8*)(pa[i] + (kk)); \
        _Pragma("unroll")                                                \
        for (int i = 0; i < 4; ++i) bv[i] = *(const f16x8*)(pb[i] + (kk)); \
    } while (0)
#define MM(av, bv)                                                       \
    _Pragma("unroll")                                                    \
    for (int mf = 0; mf < 4; ++mf)                                       \
        _Pragma("unroll")                                                \
        for (int nf = 0; nf < 4; ++nf)                                   \
            acc[mf][nf] = __builtin_amdgcn_mfma_f32_16x16x32_f16(        \
                av[mf], bv[nf], acc[mf][nf], 0, 0, 0);

    LD(a0, b0, 0);
    for (int k = 0; k < K; k += 64) {   // K multiple of 64 (768)
        LD(a1, b1, k + 32);
        MM(a0, b0);
        if (k + 64 < K) LD(a0, b0, k + 64);
        MM(a1, b1);
    }
#undef LD
#undef MM

    if constexpr (EPI == 0) {
#pragma unroll
        for (int mf = 0; mf < 4; ++mf)
#pragma unroll
            for (int nf = 0; nf < 4; ++nf)
#pragma unroll
                for (int j = 0; j < 4; ++j) {
                    int gr = m0 + wr * 64 + mf * 16 + lk * 4 + j;
                    int gc = n0 + wc * 64 + nf * 16 + l15;
                    C[(long)gr * N + gc] = acc[mf][nf][j];
                }
    } else {
        int ht = (n0 >> 6) + wc;       // [0,36): t*12 + h
        int tq = ht / NH;
        int h  = ht - tq * NH;
        int b  = m0 >> 11;             // 128-row tile never straddles a batch
        long base_bh = ((long)(b * NH + h)) * SDIM;
#pragma unroll
        for (int mf = 0; mf < 4; ++mf) {
#pragma unroll
            for (int j = 0; j < 4; ++j) {
                int gr = m0 + wr * 64 + mf * 16 + lk * 4 + j;
                int s  = gr & (SDIM - 1);
                if (tq == 2) {
#pragma unroll
                    for (int nf = 0; nf < 4; ++nf) {
                        int d = nf * 16 + l15;
                        vh[(base_bh + s) * HD + d] = (_Float16)acc[mf][nf][j];
                    }
                } else {
                    float vals[4];
#pragma unroll
                    for (int nf = 0; nf < 4; ++nf) vals[nf] = acc[mf][nf][j];
#pragma unroll
                    for (int nf = 0; nf < 4; ++nf) {
                        int d = nf * 16 + l15;
                        float cc = cosp[(long)gr * HD + d];
                        float ss = sinp[(long)gr * HD + d];
                        float pv = (nf < 2) ? -vals[nf + 2] : vals[nf - 2];
                        float o  = vals[nf] * cc + pv * ss;
                        long oidx = (base_bh + s) * HD + d;
                        if (tq == 0) qh[oidx] = (_Float16)o;
                        else         kh[oidx] = (_Float16)o;
                    }
                }
            }
        }
    }
}

// ---------------------------- MFMA attention --------------------------------
// Block = 4 waves = one (b,h, 64-query tile); key window = 192 keys.
#define SSTR 200
#define PSTR 200
__global__ __launch_bounds__(256) void attn_mfma(
    const _Float16* __restrict__ qh,
    const _Float16* __restrict__ kh,
    const _Float16* __restrict__ vh,
    _Float16* __restrict__ yh)
{
    __shared__ __align__(16) _Float16 lsVT[64 * SSTR];
    __shared__ __align__(16) _Float16 lsP [64 * PSTR];

    int bid = blockIdx.x;
    int qt  = bid & 31;
    int bh  = bid >> 5;
    int q0  = qt << 6;
    int k0  = q0 - 64;
    int tid = threadIdx.x;
    int lane = tid & 63;
    int w = tid >> 6;
    int l15 = lane & 15, lg = lane >> 4;

    const _Float16* Qb = qh + (long)bh * SDIM * HD;
    const _Float16* Kb = kh + (long)bh * SDIM * HD;
    const _Float16* Vb = vh + (long)bh * SDIM * HD;

#pragma unroll
    for (int c = 0; c < 3; ++c) {
        int rk = c * 64 + lane;
        int s  = k0 + rk;
        s = s < 0 ? 0 : (s >= SDIM ? SDIM - 1 : s);
        const f16x8* vr = (const f16x8*)(Vb + (long)s * HD + w * 16);
        f16x8 v0 = vr[0], v1 = vr[1];
#pragma unroll
        for (int e = 0; e < 8; ++e) {
            lsVT[(w * 16 + e)     * SSTR + rk] = v0[e];
            lsVT[(w * 16 + 8 + e) * SSTR + rk] = v1[e];
        }
    }

    int qrow = q0 + w * 16 + l15;
    const f16x8* qp = (const f16x8*)(Qb + (long)qrow * HD + lg * 8);
    f16x8 qa0 = qp[0];
    f16x8 qa1 = qp[4];

    float sums[4] = {0.f, 0.f, 0.f, 0.f};
    int iqb = w * 16 + lg * 4;
#pragma unroll 4
    for (int kt = 0; kt < 12; ++kt) {
        int krow = k0 + kt * 16 + l15;
        int kcl = krow < 0 ? 0 : (krow >= SDIM ? SDIM - 1 : krow);
        const f16x8* kp = (const f16x8*)(Kb + (long)kcl * HD + lg * 8);
        f16x8 kb0 = kp[0], kb1 = kp[4];
        f32x4 acc = {0.f, 0.f, 0.f, 0.f};
        acc = __builtin_amdgcn_mfma_f32_16x16x32_f16(qa0, kb0, acc, 0, 0, 0);
        acc = __builtin_amdgcn_mfma_f32_16x16x32_f16(qa1, kb1, acc, 0, 0, 0);
        int jk = kt * 16 + l15;
        bool kin = (krow >= 0) && (krow < SDIM);
#pragma unroll
        for (int j = 0; j < 4; ++j) {
            int i = iqb + j;
            bool valid = kin && (jk >= i) && (jk <= i + 128);
            float p = valid ? __expf(acc[j] * 0.125f) : 0.f;
            sums[j] += p;
            lsP[(w * 16 + lg * 4 + j) * PSTR + jk] = (_Float16)p;
        }
    }

#pragma unroll
    for (int m = 1; m < 16; m <<= 1) {
#pragma unroll
        for (int j = 0; j < 4; ++j)
            sums[j] += __shfl_xor(sums[j], m, 64);
    }
    float inv[4];
#pragma unroll
    for (int j = 0; j < 4; ++j) inv[j] = 1.f / sums[j];

    __syncthreads();

    f32x4 accy[4] = {};
    const _Float16* prow = &lsP[(w * 16 + l15) * PSTR + lg * 8];
#pragma unroll
    for (int kc = 0; kc < 6; ++kc) {
        f16x8 pa = *(const f16x8*)(prow + kc * 32);
#pragma unroll
        for (int dt = 0; dt < 4; ++dt) {
            f16x8 vb = *(const f16x8*)&lsVT[(dt * 16 + l15) * SSTR + kc * 32 + lg * 8];
            accy[dt] = __builtin_amdgcn_mfma_f32_16x16x32_f16(pa, vb, accy[dt], 0, 0, 0);
        }
    }

    int b = bh / NH, h = bh - (bh / NH) * NH;
    long outbase = ((long)b * SDIM) * HDIM + (long)h * HD;
#pragma unroll
    for (int dt = 0; dt < 4; ++dt) {
#pragma unroll
        for (int j = 0; j < 4; ++j) {
            int srow = q0 + w * 16 + lg * 4 + j;
            yh[outbase + (long)srow * HDIM + dt * 16 + l15] =
                (_Float16)(accy[dt][j] * inv[j]);
        }
    }
}

// ---------------------------------------------------------------------------
extern "C" void kernel_launch(void* const* d_in, const int* in_sizes, int n_in,
                              void* d_out, int out_size, void* d_ws, size_t ws_size,
                              hipStream_t stream)
{
    const float* x    = (const float*)d_in[0];
    const float* cosp = (const float*)d_in[1];
    const float* sinp = (const float*)d_in[2];
    const float* Wqkv = (const float*)d_in[3];
    const float* Wo   = (const float*)d_in[4];
    float* out = (float*)d_out;

    char* ws = (char*)d_ws;
    _Float16* xh    = (_Float16*)(ws);                    // 12,582,912
    _Float16* wqkvh = (_Float16*)(ws + 12582912);         //  3,538,944
    _Float16* woh   = (_Float16*)(ws + 16121856);         //  1,179,648
    _Float16* qh    = (_Float16*)(ws + 17301504);         // 12,582,912
    _Float16* kh    = (_Float16*)(ws + 29884416);         // 12,582,912
    _Float16* vh    = (_Float16*)(ws + 42467328);         // 12,582,912
    _Float16* yh    = (_Float16*)(ws + 55050240);         // 12,582,912 -> 67,633,152 total

    // 1) convert inputs to fp16
    cvt_f32_f16<<<(MROWS * HDIM / 8 + 255) / 256, 256, 0, stream>>>(x, xh, MROWS * HDIM / 8);
    cvt_f32_f16<<<(NQKV * HDIM / 8 + 255) / 256, 256, 0, stream>>>(Wqkv, wqkvh, NQKV * HDIM / 8);
    cvt_f32_f16<<<(HDIM * HDIM / 8 + 255) / 256, 256, 0, stream>>>(Wo, woh, HDIM * HDIM / 8);

    // 2) QKV gemm with fused RoPE + scatter epilogue (direct-global, no LDS)
    {
        dim3 grid((MROWS / 128) * (NQKV / 128));   // 64*18 = 1152
        gemm_direct<1><<<grid, 256, 0, stream>>>(
            xh, wqkvh, nullptr, cosp, sinp, qh, kh, vh, MROWS, NQKV, HDIM);
    }

    // 3) sliding-window MFMA attention
    {
        dim3 grid(BDIM * NH * (SDIM / 64));        // 1536
        attn_mfma<<<grid, 256, 0, stream>>>(qh, kh, vh, yh);
    }

    // 4) output projection (direct-global, no LDS)
    {
        dim3 grid((MROWS / 128) * (HDIM / 128));   // 64*6 = 384
        gemm_direct<0><<<grid, 256, 0, stream>>>(
            yh, woh, out, nullptr, nullptr, nullptr, nullptr, nullptr,
            MROWS, HDIM, HDIM);
    }
}

// Round 9
// 152.699 us; speedup vs baseline: 1.4478x; 1.4478x over previous
//
#include <hip/hip_runtime.h>

// ---------------------------------------------------------------------------
// ModernBertAttention: x[4,2048,768] -> QKV gemm(+RoPE) -> sliding-window
// MFMA attention (window=64) -> out-proj gemm.  out f32 [4,2048,768].
// ---------------------------------------------------------------------------

typedef __attribute__((ext_vector_type(8))) _Float16 f16x8;
typedef __attribute__((ext_vector_type(4))) float    f32x4;

#define BDIM 4
#define SDIM 2048
#define HDIM 768
#define NH   12
#define HD   64
#define NQKV 2304   // 3*HDIM
#define MROWS 8192  // B*S

// ---------------------------------------------------------------------------
__device__ __forceinline__ void gload16(const void* g, void* l) {
    __builtin_amdgcn_global_load_lds(
        (__attribute__((address_space(1))) void*)(g),
        (__attribute__((address_space(3))) void*)(l),
        16, 0, 0);
}

// --------------------------- f32 -> f16 convert ----------------------------
__global__ __launch_bounds__(256) void cvt_f32_f16(
    const float* __restrict__ src, _Float16* __restrict__ dst, int n8)
{
    int i = blockIdx.x * 256 + threadIdx.x;
    if (i >= n8) return;
    const float4* s4 = (const float4*)src + (long)i * 2;
    float4 a = s4[0], b = s4[1];
    f16x8 o;
    o[0] = (_Float16)a.x; o[1] = (_Float16)a.y;
    o[2] = (_Float16)a.z; o[3] = (_Float16)a.w;
    o[4] = (_Float16)b.x; o[5] = (_Float16)b.y;
    o[6] = (_Float16)b.z; o[7] = (_Float16)b.w;
    *((f16x8*)dst + i) = o;
}

// --------------------------- hybrid GEMM ------------------------------------
// C[M,N] = A[M,K]*Bt[N,K]^T, fp16 in, fp32 acc. Tile 128x128, 4 waves (2x2),
// BK=64, 12 K-tiles.
// A: LDS-staged (global_load_lds, double-buffered, XOR-swizzled both sides:
//    pre-swizzled global source column + swizzled ds_read -> conflict-free
//    b128 at 128B row stride; verified 0 conflicts in R7).
// B: weights (<=3.5MB, L2/L1-hot; 16 rows x 64B contiguous per frag read) are
//    read DIRECTLY from global into registers each K-tile -- no LDS, no
//    barrier coupling; compiler schedules them against the MFMA cluster.
// Per block-k-step LDS traffic halves (48->24KB) vs staging both operands.
// EPI==0: plain f32 C store.
// EPI==1: RoPE on q/k + scatter q/k/v (f16) to [B,nh,S,hd].
template <int EPI>
__global__ __launch_bounds__(256) void gemm_hybrid(
    const _Float16* __restrict__ A,
    const _Float16* __restrict__ Bt,
    float* __restrict__ C,
    const float* __restrict__ cosp,
    const float* __restrict__ sinp,
    _Float16* __restrict__ qh,
    _Float16* __restrict__ kh,
    _Float16* __restrict__ vh,
    int M, int N, int K)
{
    __shared__ __align__(16) _Float16 lsA[2][128 * 64];   // 16KB x2

    int nTn = N >> 7;
    int nwg = gridDim.x;
    int bid = blockIdx.x;
    int cpx = nwg >> 3;                       // grids are %8==0
    int wg  = (bid & 7) * cpx + (bid >> 3);   // XCD-aware bijective swizzle
    int tm = wg / nTn, tn = wg % nTn;
    int m0 = tm << 7, n0 = tn << 7;

    int tid  = threadIdx.x;
    int lane = tid & 63;
    int w    = tid >> 6;
    int wr   = w >> 1, wc = w & 1;
    int l15  = lane & 15, lk = lane >> 4;

    f32x4 acc[4][4] = {};

    // ---- A staging: thread covers rows (tid>>3)+i*32, phys granule tid&7.
    // global_load_lds writes linearly (dst byte = wavebase + lane*16), so the
    // swizzle lives in the SOURCE column: logical granule = (tid&7)^(row&7).
    int arow = tid >> 3;                       // 0..31
    int gsrc = (tid & 7) ^ (arow & 7);         // (i*32)&7==0 -> same for all i
    const _Float16* gA = A + (long)(m0 + arow) * K + gsrc * 8;
    const long rstep = (long)32 * K;
    _Float16* la0 = &lsA[0][tid * 8];
    _Float16* la1 = &lsA[1][tid * 8];

    auto STAGE_A = [&](_Float16* la, int t) {
#pragma unroll
        for (int i = 0; i < 4; ++i)
            gload16(gA + i * rstep + t * 64, la + i * 2048);
    };

    // ---- B direct-global fragment pointers (row=l15 within frag, k=lk*8+e)
    const _Float16* pb[4];
#pragma unroll
    for (int nf = 0; nf < 4; ++nf)
        pb[nf] = Bt + (long)(n0 + wc * 64 + nf * 16 + l15) * K + lk * 8;

    // ---- A frag read (swizzled): row r=wr*64+mf*16+l15, granule (ks*4+lk)^(l15&7)
    int xg = l15 & 7;
    auto RD_A = [&](const _Float16* base, int ks, f16x8* af) {
#pragma unroll
        for (int mf = 0; mf < 4; ++mf) {
            int r = wr * 64 + mf * 16 + l15;
            af[mf] = *(const f16x8*)&base[r * 64 + ((((ks << 2) | lk) ^ xg) << 3)];
        }
    };

    const int NT = K >> 6;   // 12

    STAGE_A(la0, 0);
    asm volatile("s_waitcnt vmcnt(0)" ::: "memory");
    __builtin_amdgcn_s_barrier();

    int cur = 0;
    for (int t = 0; t < NT; ++t) {
        const _Float16* a_cur = cur ? lsA[1] : lsA[0];
        bool more = (t + 1 < NT);

        // stage next A tile first (latency hides under this iter's MFMAs)
        if (more) STAGE_A(cur ? la0 : la1, t + 1);

        // B frags for the whole K-tile, straight from global (L1/L2-hot)
        f16x8 bf0[4], bf1[4];
        int kk = t * 64;
#pragma unroll
        for (int nf = 0; nf < 4; ++nf) bf0[nf] = *(const f16x8*)(pb[nf] + kk);
#pragma unroll
        for (int nf = 0; nf < 4; ++nf) bf1[nf] = *(const f16x8*)(pb[nf] + kk + 32);

        f16x8 af[4];
        RD_A(a_cur, 0, af);
#pragma unroll
        for (int mf = 0; mf < 4; ++mf)
#pragma unroll
            for (int nf = 0; nf < 4; ++nf)
                acc[mf][nf] = __builtin_amdgcn_mfma_f32_16x16x32_f16(
                    af[mf], bf0[nf], acc[mf][nf], 0, 0, 0);
        RD_A(a_cur, 1, af);
#pragma unroll
        for (int mf = 0; mf < 4; ++mf)
#pragma unroll
            for (int nf = 0; nf < 4; ++nf)
                acc[mf][nf] = __builtin_amdgcn_mfma_f32_16x16x32_f16(
                    af[mf], bf1[nf], acc[mf][nf], 0, 0, 0);

        // next-tile A resident; B already consumed (compiler-tracked waits)
        if (more) {
            asm volatile("s_waitcnt vmcnt(0)" ::: "memory");
            __builtin_amdgcn_s_barrier();
        }
        cur ^= 1;
    }

    if constexpr (EPI == 0) {
#pragma unroll
        for (int mf = 0; mf < 4; ++mf)
#pragma unroll
            for (int nf = 0; nf < 4; ++nf)
#pragma unroll
                for (int j = 0; j < 4; ++j) {
                    int gr = m0 + wr * 64 + mf * 16 + lk * 4 + j;
                    int gc = n0 + wc * 64 + nf * 16 + l15;
                    C[(long)gr * N + gc] = acc[mf][nf][j];
                }
    } else {
        int ht = (n0 >> 6) + wc;       // [0,36): t*12 + h
        int tq = ht / NH;
        int h  = ht - tq * NH;
        int b  = m0 >> 11;             // 128-row tile never straddles a batch
        long base_bh = ((long)(b * NH + h)) * SDIM;
#pragma unroll
        for (int mf = 0; mf < 4; ++mf) {
#pragma unroll
            for (int j = 0; j < 4; ++j) {
                int gr = m0 + wr * 64 + mf * 16 + lk * 4 + j;
                int s  = gr & (SDIM - 1);
                if (tq == 2) {
#pragma unroll
                    for (int nf = 0; nf < 4; ++nf) {
                        int d = nf * 16 + l15;
                        vh[(base_bh + s) * HD + d] = (_Float16)acc[mf][nf][j];
                    }
                } else {
                    float vals[4];
#pragma unroll
                    for (int nf = 0; nf < 4; ++nf) vals[nf] = acc[mf][nf][j];
#pragma unroll
                    for (int nf = 0; nf < 4; ++nf) {
                        int d = nf * 16 + l15;
                        float cc = cosp[(long)gr * HD + d];
                        float ss = sinp[(long)gr * HD + d];
                        float pv = (nf < 2) ? -vals[nf + 2] : vals[nf - 2];
                        float o  = vals[nf] * cc + pv * ss;
                        long oidx = (base_bh + s) * HD + d;
                        if (tq == 0) qh[oidx] = (_Float16)o;
                        else         kh[oidx] = (_Float16)o;
                    }
                }
            }
        }
    }
}

// ---------------------------- MFMA attention --------------------------------
// Block = 4 waves = one (b,h, 64-query tile); key window = 192 keys.
#define SSTR 200
#define PSTR 200
__global__ __launch_bounds__(256) void attn_mfma(
    const _Float16* __restrict__ qh,
    const _Float16* __restrict__ kh,
    const _Float16* __restrict__ vh,
    _Float16* __restrict__ yh)
{
    __shared__ __align__(16) _Float16 lsVT[64 * SSTR];
    __shared__ __align__(16) _Float16 lsP [64 * PSTR];

    int bid = blockIdx.x;
    int qt  = bid & 31;
    int bh  = bid >> 5;
    int q0  = qt << 6;
    int k0  = q0 - 64;
    int tid = threadIdx.x;
    int lane = tid & 63;
    int w = tid >> 6;
    int l15 = lane & 15, lg = lane >> 4;

    const _Float16* Qb = qh + (long)bh * SDIM * HD;
    const _Float16* Kb = kh + (long)bh * SDIM * HD;
    const _Float16* Vb = vh + (long)bh * SDIM * HD;

#pragma unroll
    for (int c = 0; c < 3; ++c) {
        int rk = c * 64 + lane;
        int s  = k0 + rk;
        s = s < 0 ? 0 : (s >= SDIM ? SDIM - 1 : s);
        const f16x8* vr = (const f16x8*)(Vb + (long)s * HD + w * 16);
        f16x8 v0 = vr[0], v1 = vr[1];
#pragma unroll
        for (int e = 0; e < 8; ++e) {
            lsVT[(w * 16 + e)     * SSTR + rk] = v0[e];
            lsVT[(w * 16 + 8 + e) * SSTR + rk] = v1[e];
        }
    }

    int qrow = q0 + w * 16 + l15;
    const f16x8* qp = (const f16x8*)(Qb + (long)qrow * HD + lg * 8);
    f16x8 qa0 = qp[0];
    f16x8 qa1 = qp[4];

    float sums[4] = {0.f, 0.f, 0.f, 0.f};
    int iqb = w * 16 + lg * 4;
#pragma unroll 4
    for (int kt = 0; kt < 12; ++kt) {
        int krow = k0 + kt * 16 + l15;
        int kcl = krow < 0 ? 0 : (krow >= SDIM ? SDIM - 1 : krow);
        const f16x8* kp = (const f16x8*)(Kb + (long)kcl * HD + lg * 8);
        f16x8 kb0 = kp[0], kb1 = kp[4];
        f32x4 acc = {0.f, 0.f, 0.f, 0.f};
        acc = __builtin_amdgcn_mfma_f32_16x16x32_f16(qa0, kb0, acc, 0, 0, 0);
        acc = __builtin_amdgcn_mfma_f32_16x16x32_f16(qa1, kb1, acc, 0, 0, 0);
        int jk = kt * 16 + l15;
        bool kin = (krow >= 0) && (krow < SDIM);
#pragma unroll
        for (int j = 0; j < 4; ++j) {
            int i = iqb + j;
            bool valid = kin && (jk >= i) && (jk <= i + 128);
            float p = valid ? __expf(acc[j] * 0.125f) : 0.f;
            sums[j] += p;
            lsP[(w * 16 + lg * 4 + j) * PSTR + jk] = (_Float16)p;
        }
    }

#pragma unroll
    for (int m = 1; m < 16; m <<= 1) {
#pragma unroll
        for (int j = 0; j < 4; ++j)
            sums[j] += __shfl_xor(sums[j], m, 64);
    }
    float inv[4];
#pragma unroll
    for (int j = 0; j < 4; ++j) inv[j] = 1.f / sums[j];

    __syncthreads();

    f32x4 accy[4] = {};
    const _Float16* prow = &lsP[(w * 16 + l15) * PSTR + lg * 8];
#pragma unroll
    for (int kc = 0; kc < 6; ++kc) {
        f16x8 pa = *(const f16x8*)(prow + kc * 32);
#pragma unroll
        for (int dt = 0; dt < 4; ++dt) {
            f16x8 vb = *(const f16x8*)&lsVT[(dt * 16 + l15) * SSTR + kc * 32 + lg * 8];
            accy[dt] = __builtin_amdgcn_mfma_f32_16x16x32_f16(pa, vb, accy[dt], 0, 0, 0);
        }
    }

    int b = bh / NH, h = bh - (bh / NH) * NH;
    long outbase = ((long)b * SDIM) * HDIM + (long)h * HD;
#pragma unroll
    for (int dt = 0; dt < 4; ++dt) {
#pragma unroll
        for (int j = 0; j < 4; ++j) {
            int srow = q0 + w * 16 + lg * 4 + j;
            yh[outbase + (long)srow * HDIM + dt * 16 + l15] =
                (_Float16)(accy[dt][j] * inv[j]);
        }
    }
}

// ---------------------------------------------------------------------------
extern "C" void kernel_launch(void* const* d_in, const int* in_sizes, int n_in,
                              void* d_out, int out_size, void* d_ws, size_t ws_size,
                              hipStream_t stream)
{
    const float* x    = (const float*)d_in[0];
    const float* cosp = (const float*)d_in[1];
    const float* sinp = (const float*)d_in[2];
    const float* Wqkv = (const float*)d_in[3];
    const float* Wo   = (const float*)d_in[4];
    float* out = (float*)d_out;

    char* ws = (char*)d_ws;
    _Float16* xh    = (_Float16*)(ws);                    // 12,582,912
    _Float16* wqkvh = (_Float16*)(ws + 12582912);         //  3,538,944
    _Float16* woh   = (_Float16*)(ws + 16121856);         //  1,179,648
    _Float16* qh    = (_Float16*)(ws + 17301504);         // 12,582,912
    _Float16* kh    = (_Float16*)(ws + 29884416);         // 12,582,912
    _Float16* vh    = (_Float16*)(ws + 42467328);         // 12,582,912
    _Float16* yh    = (_Float16*)(ws + 55050240);         // 12,582,912 -> 67,633,152 total

    // 1) convert inputs to fp16
    cvt_f32_f16<<<(MROWS * HDIM / 8 + 255) / 256, 256, 0, stream>>>(x, xh, MROWS * HDIM / 8);
    cvt_f32_f16<<<(NQKV * HDIM / 8 + 255) / 256, 256, 0, stream>>>(Wqkv, wqkvh, NQKV * HDIM / 8);
    cvt_f32_f16<<<(HDIM * HDIM / 8 + 255) / 256, 256, 0, stream>>>(Wo, woh, HDIM * HDIM / 8);

    // 2) QKV gemm with fused RoPE + scatter epilogue (hybrid: A->LDS, B direct)
    {
        dim3 grid((MROWS / 128) * (NQKV / 128));   // 64*18 = 1152
        gemm_hybrid<1><<<grid, 256, 0, stream>>>(
            xh, wqkvh, nullptr, cosp, sinp, qh, kh, vh, MROWS, NQKV, HDIM);
    }

    // 3) sliding-window MFMA attention
    {
        dim3 grid(BDIM * NH * (SDIM / 64));        // 1536
        attn_mfma<<<grid, 256, 0, stream>>>(qh, kh, vh, yh);
    }

    // 4) output projection (hybrid)
    {
        dim3 grid((MROWS / 128) * (HDIM / 128));   // 64*6 = 384
        gemm_hybrid<0><<<grid, 256, 0, stream>>>(
            yh, woh, out, nullptr, nullptr, nullptr, nullptr, nullptr,
            MROWS, HDIM, HDIM);
    }
}

// Round 10
// 114.707 us; speedup vs baseline: 1.9273x; 1.3312x over previous
//
#include <hip/hip_runtime.h>

// ---------------------------------------------------------------------------
// ModernBertAttention: x[4,2048,768] -> QKV gemm(+cvt+RoPE fused) ->
// sliding-window MFMA attention (window=64) -> out-proj gemm.
// out f32 [4,2048,768].
// ---------------------------------------------------------------------------

typedef __attribute__((ext_vector_type(8))) _Float16 f16x8;
typedef __attribute__((ext_vector_type(4))) float    f32x4;

#define BDIM 4
#define SDIM 2048
#define HDIM 768
#define NH   12
#define HD   64
#define NQKV 2304   // 3*HDIM
#define MROWS 8192  // B*S

// ---------------------------------------------------------------------------
__device__ __forceinline__ void gload16(const void* g, void* l) {
    __builtin_amdgcn_global_load_lds(
        (__attribute__((address_space(1))) void*)(g),
        (__attribute__((address_space(3))) void*)(l),
        16, 0, 0);
}

// ----------------------- weight f32 -> f16 convert --------------------------
__global__ __launch_bounds__(256) void cvt_weights(
    const float* __restrict__ wqkv, const float* __restrict__ wo,
    _Float16* __restrict__ dq, _Float16* __restrict__ dwo)
{
    const int n1 = NQKV * HDIM / 8;   // 221184
    const int n2 = HDIM * HDIM / 8;   //  73728
    int i = blockIdx.x * 256 + threadIdx.x;
    const float* s; _Float16* d; int j;
    if (i < n1)            { s = wqkv; d = dq;  j = i; }
    else if (i < n1 + n2)  { s = wo;   d = dwo; j = i - n1; }
    else return;
    const float4* s4 = (const float4*)s + (long)j * 2;
    float4 a = s4[0], b = s4[1];
    f16x8 o;
    o[0] = (_Float16)a.x; o[1] = (_Float16)a.y;
    o[2] = (_Float16)a.z; o[3] = (_Float16)a.w;
    o[4] = (_Float16)b.x; o[5] = (_Float16)b.y;
    o[6] = (_Float16)b.z; o[7] = (_Float16)b.w;
    *((f16x8*)d + j) = o;
}

// ----------------- QKV GEMM with fused f32->f16 A-staging -------------------
// C = x[8192,768](f32) * Wqkv^T, tile 128x128, 4 waves, BK=64, 12 K-tiles.
// A: reg-staged (f32 global -> cvt -> swizzled ds_write). Fuses the x
//    conversion kernel into staging (T14 issue-early/write-late).
// B: global_load_lds, linear dest + pre-swizzled source column.
// Both LDS tiles XOR-swizzled: phys_granule = logical ^ (row&7) -> verified
// conflict-free b128 reads at 128B row stride (R7: SQ_LDS_BANK_CONFLICT=0).
// One barrier + one vmcnt(0) per K-tile; prefetch issued AFTER the barrier
// (safe to overwrite freed buffer), waited one full MFMA block later.
// Epilogue: RoPE on q/k, scatter q/k/v (f16) to [B,nh,S,hd].
__global__ __launch_bounds__(256) void gemm_qkv(
    const float* __restrict__ A,         // x f32
    const _Float16* __restrict__ Bt,     // wqkvh f16 [2304][768]
    const float* __restrict__ cosp,
    const float* __restrict__ sinp,
    _Float16* __restrict__ qh,
    _Float16* __restrict__ kh,
    _Float16* __restrict__ vh)
{
    const int K = HDIM;
    __shared__ __align__(16) _Float16 lsA[2][128 * 64];   // 16KB x2
    __shared__ __align__(16) _Float16 lsB[2][128 * 64];   // 16KB x2

    const int nTn = NQKV >> 7;                // 18
    int nwg = gridDim.x;
    int bid = blockIdx.x;
    int cpx = nwg >> 3;
    int wg  = (bid & 7) * cpx + (bid >> 3);   // XCD-aware bijective swizzle
    int tm = wg / nTn, tn = wg % nTn;
    int m0 = tm << 7, n0 = tn << 7;

    int tid  = threadIdx.x;
    int lane = tid & 63;
    int w    = tid >> 6;
    int wr   = w >> 1, wc = w & 1;
    int l15  = lane & 15, lk = lane >> 4;

    f32x4 acc[4][4] = {};

    // ---- A reg-staging: thread covers rows (tid>>3)+32i, logical granule tid&7
    int arow = tid >> 3;
    int ag   = tid & 7;
    const float* gA = A + (long)(m0 + arow) * K + ag * 8;
    int awr = arow * 64 + ((ag ^ (arow & 7)) << 3);   // swizzled f16 index
    float4 r0, r1, r2, r3, r4, r5, r6, r7;            // staged f32 (2 per row-group)

    // ---- B staging via global_load_lds: linear dest, pre-swizzled source
    int bg = (tid & 7) ^ ((tid >> 3) & 7);
    const _Float16* gB = Bt + (long)(n0 + (tid >> 3)) * K + bg * 8;

#define ALOAD(t) do {                                                   \
        const float* p_ = gA + (t) * 64;                                \
        r0 = ((const float4*)(p_            ))[0];                      \
        r1 = ((const float4*)(p_            ))[1];                      \
        r2 = ((const float4*)(p_ +  32L * K))[0];                       \
        r3 = ((const float4*)(p_ +  32L * K))[1];                       \
        r4 = ((const float4*)(p_ +  64L * K))[0];                       \
        r5 = ((const float4*)(p_ +  64L * K))[1];                       \
        r6 = ((const float4*)(p_ +  96L * K))[0];                       \
        r7 = ((const float4*)(p_ +  96L * K))[1];                       \
    } while (0)

#define CVT8(lo, hi, dst) do {                                          \
        f16x8 v_;                                                       \
        v_[0] = (_Float16)(lo).x; v_[1] = (_Float16)(lo).y;             \
        v_[2] = (_Float16)(lo).z; v_[3] = (_Float16)(lo).w;             \
        v_[4] = (_Float16)(hi).x; v_[5] = (_Float16)(hi).y;             \
        v_[6] = (_Float16)(hi).z; v_[7] = (_Float16)(hi).w;             \
        *(f16x8*)(dst) = v_;                                            \
    } while (0)

#define AWRITE(buf) do {                                                \
        CVT8(r0, r1, &lsA[buf][awr]);                                   \
        CVT8(r2, r3, &lsA[buf][awr + 2048]);                            \
        CVT8(r4, r5, &lsA[buf][awr + 4096]);                            \
        CVT8(r6, r7, &lsA[buf][awr + 6144]);                            \
    } while (0)

#define STAGE_B(buf, t) do {                                            \
        gload16(gB + (t) * 64,            &lsB[buf][tid * 8]);          \
        gload16(gB + (t) * 64 + 32L * K,  &lsB[buf][tid * 8 + 2048]);   \
        gload16(gB + (t) * 64 + 64L * K,  &lsB[buf][tid * 8 + 4096]);   \
        gload16(gB + (t) * 64 + 96L * K,  &lsB[buf][tid * 8 + 6144]);   \
    } while (0)

    // frag read: row rbase+mf*16+l15, phys granule (ks*4+lk) ^ (l15&7)
    int xg = l15 & 7;
#define RD(base, rbase, ks, f) do {                                     \
        _Pragma("unroll")                                               \
        for (int mf_ = 0; mf_ < 4; ++mf_) {                             \
            int row_ = (rbase) + mf_ * 16 + l15;                        \
            (f)[mf_] = *(const f16x8*)&(base)[row_ * 64 +               \
                (((((ks) << 2) | lk) ^ xg) << 3)];                      \
        }                                                               \
    } while (0)

    const int NT = K >> 6;   // 12

    // prologue
    ALOAD(0);
    STAGE_B(0, 0);
    asm volatile("s_waitcnt vmcnt(0)" ::: "memory");
    AWRITE(0);
    ALOAD(1);
    STAGE_B(1, 1);
    asm volatile("s_waitcnt lgkmcnt(0)" ::: "memory");
    __builtin_amdgcn_s_barrier();

    int cur = 0;
    for (int t = 0; t < NT; ++t) {
        int nxt = cur ^ 1;
        f16x8 af[4], bf[4];

        RD(lsA[cur], wr * 64, 0, af);
        RD(lsB[cur], wc * 64, 0, bf);
#pragma unroll
        for (int mf = 0; mf < 4; ++mf)
#pragma unroll
            for (int nf = 0; nf < 4; ++nf)
                acc[mf][nf] = __builtin_amdgcn_mfma_f32_16x16x32_f16(
                    af[mf], bf[nf], acc[mf][nf], 0, 0, 0);

        RD(lsA[cur], wr * 64, 1, af);
        RD(lsB[cur], wc * 64, 1, bf);
#pragma unroll
        for (int mf = 0; mf < 4; ++mf)
#pragma unroll
            for (int nf = 0; nf < 4; ++nf)
                acc[mf][nf] = __builtin_amdgcn_mfma_f32_16x16x32_f16(
                    af[mf], bf[nf], acc[mf][nf], 0, 0, 0);

        if (t + 1 < NT) {
            asm volatile("s_waitcnt vmcnt(0)" ::: "memory");  // A regs + B(t+1) landed
            AWRITE(nxt);                                      // A(t+1) -> LDS
            asm volatile("s_waitcnt lgkmcnt(0)" ::: "memory");
            __builtin_amdgcn_s_barrier();                     // nxt ready; cur free
            if (t + 2 < NT) {                                 // prefetch into freed buf
                ALOAD(t + 2);
                STAGE_B(cur, t + 2);
            }
        }
        cur = nxt;
    }
#undef ALOAD
#undef CVT8
#undef AWRITE
#undef STAGE_B
#undef RD

    // ---- epilogue: RoPE + scatter ----
    int ht = (n0 >> 6) + wc;       // [0,36): t*12 + h
    int tq = ht / NH;
    int h  = ht - tq * NH;
    int b  = m0 >> 11;
    long base_bh = ((long)(b * NH + h)) * SDIM;
#pragma unroll
    for (int mf = 0; mf < 4; ++mf) {
#pragma unroll
        for (int j = 0; j < 4; ++j) {
            int gr = m0 + wr * 64 + mf * 16 + lk * 4 + j;
            int s  = gr & (SDIM - 1);
            if (tq == 2) {
#pragma unroll
                for (int nf = 0; nf < 4; ++nf) {
                    int d = nf * 16 + l15;
                    vh[(base_bh + s) * HD + d] = (_Float16)acc[mf][nf][j];
                }
            } else {
                float vals[4];
#pragma unroll
                for (int nf = 0; nf < 4; ++nf) vals[nf] = acc[mf][nf][j];
#pragma unroll
                for (int nf = 0; nf < 4; ++nf) {
                    int d = nf * 16 + l15;
                    float cc = cosp[(long)gr * HD + d];
                    float ss = sinp[(long)gr * HD + d];
                    float pv = (nf < 2) ? -vals[nf + 2] : vals[nf - 2];
                    float o  = vals[nf] * cc + pv * ss;
                    long oidx = (base_bh + s) * HD + d;
                    if (tq == 0) qh[oidx] = (_Float16)o;
                    else         kh[oidx] = (_Float16)o;
                }
            }
        }
    }
}

// ------------------------- out-proj GEMM (R5 kernel) ------------------------
// C[M,N] = A[M,K]*Bt[N,K]^T, f16 in, f32 out. 128x128, BK=32, counted vmcnt.
__global__ __launch_bounds__(256) void gemm_op(
    const _Float16* __restrict__ A,
    const _Float16* __restrict__ Bt,
    float* __restrict__ C,
    int M, int N, int K)
{
    __shared__ __align__(16) _Float16 lsA[2][128 * 32];
    __shared__ __align__(16) _Float16 lsB[2][128 * 32];

    int nTn = N >> 7;
    int nwg = gridDim.x;
    int bid = blockIdx.x;
    int cpx = nwg >> 3;
    int wg  = (bid & 7) * cpx + (bid >> 3);
    int tm = wg / nTn, tn = wg % nTn;
    int m0 = tm << 7, n0 = tn << 7;

    int tid  = threadIdx.x;
    int lane = tid & 63;
    int w    = tid >> 6;
    int wr   = w >> 1, wc = w & 1;
    int l15  = lane & 15, lk = lane >> 4;

    f32x4 acc[4][4] = {};

    int srow = tid >> 2;
    int scol = (tid & 3) << 3;
    const _Float16* ga0 = A  + (long)(m0 + srow) * K + scol;
    const _Float16* gb0 = Bt + (long)(n0 + srow) * K + scol;
    const long gstep = (long)64 * K;
    _Float16* laP[2] = { &lsA[0][tid * 8], &lsA[1][tid * 8] };
    _Float16* lbP[2] = { &lsB[0][tid * 8], &lsB[1][tid * 8] };

    const int NK = K >> 5;

#define STAGE(buf, t) do {                                   \
        const _Float16* ga_ = ga0 + (t) * 32;                \
        const _Float16* gb_ = gb0 + (t) * 32;                \
        gload16(ga_,         laP[buf]);                      \
        gload16(ga_ + gstep, laP[buf] + 2048);               \
        gload16(gb_,         lbP[buf]);                      \
        gload16(gb_ + gstep, lbP[buf] + 2048);               \
    } while (0)

    STAGE(0, 0);
    STAGE(1, 1);
    asm volatile("s_waitcnt vmcnt(4)" ::: "memory");
    __builtin_amdgcn_s_barrier();

    int cur = 0;
    for (int it = 0; it < NK; ++it) {
        f16x8 af[4], bfr[4];
#pragma unroll
        for (int m = 0; m < 4; ++m)
            af[m] = *(const f16x8*)&lsA[cur][(wr * 64 + m * 16 + l15) * 32 + lk * 8];
#pragma unroll
        for (int n = 0; n < 4; ++n)
            bfr[n] = *(const f16x8*)&lsB[cur][(wc * 64 + n * 16 + l15) * 32 + lk * 8];

        asm volatile("s_waitcnt lgkmcnt(0)" ::: "memory");
        __builtin_amdgcn_s_barrier();

        if (it + 2 < NK) STAGE(cur, it + 2);

#pragma unroll
        for (int m = 0; m < 4; ++m)
#pragma unroll
            for (int n = 0; n < 4; ++n)
                acc[m][n] = __builtin_amdgcn_mfma_f32_16x16x32_f16(
                    af[m], bfr[n], acc[m][n], 0, 0, 0);

        if (it + 1 < NK) {
            if (it + 2 < NK)
                asm volatile("s_waitcnt vmcnt(4)" ::: "memory");
            else
                asm volatile("s_waitcnt vmcnt(0)" ::: "memory");
            __builtin_amdgcn_s_barrier();
        }
        cur ^= 1;
    }
#undef STAGE

#pragma unroll
    for (int m = 0; m < 4; ++m)
#pragma unroll
        for (int n = 0; n < 4; ++n)
#pragma unroll
            for (int j = 0; j < 4; ++j) {
                int gr = m0 + wr * 64 + m * 16 + lk * 4 + j;
                int gc = n0 + wc * 64 + n * 16 + l15;
                C[(long)gr * N + gc] = acc[m][n][j];
            }
}

// ---------------------------- MFMA attention --------------------------------
// Block = 4 waves = one (b,h, 64-query tile); key window = 192 keys.
#define SSTR 200
#define PSTR 200
__global__ __launch_bounds__(256) void attn_mfma(
    const _Float16* __restrict__ qh,
    const _Float16* __restrict__ kh,
    const _Float16* __restrict__ vh,
    _Float16* __restrict__ yh)
{
    __shared__ __align__(16) _Float16 lsVT[64 * SSTR];
    __shared__ __align__(16) _Float16 lsP [64 * PSTR];

    int bid = blockIdx.x;
    int qt  = bid & 31;
    int bh  = bid >> 5;
    int q0  = qt << 6;
    int k0  = q0 - 64;
    int tid = threadIdx.x;
    int lane = tid & 63;
    int w = tid >> 6;
    int l15 = lane & 15, lg = lane >> 4;

    const _Float16* Qb = qh + (long)bh * SDIM * HD;
    const _Float16* Kb = kh + (long)bh * SDIM * HD;
    const _Float16* Vb = vh + (long)bh * SDIM * HD;

#pragma unroll
    for (int c = 0; c < 3; ++c) {
        int rk = c * 64 + lane;
        int s  = k0 + rk;
        s = s < 0 ? 0 : (s >= SDIM ? SDIM - 1 : s);
        const f16x8* vr = (const f16x8*)(Vb + (long)s * HD + w * 16);
        f16x8 v0 = vr[0], v1 = vr[1];
#pragma unroll
        for (int e = 0; e < 8; ++e) {
            lsVT[(w * 16 + e)     * SSTR + rk] = v0[e];
            lsVT[(w * 16 + 8 + e) * SSTR + rk] = v1[e];
        }
    }

    int qrow = q0 + w * 16 + l15;
    const f16x8* qp = (const f16x8*)(Qb + (long)qrow * HD + lg * 8);
    f16x8 qa0 = qp[0];
    f16x8 qa1 = qp[4];

    float sums[4] = {0.f, 0.f, 0.f, 0.f};
    int iqb = w * 16 + lg * 4;
#pragma unroll 4
    for (int kt = 0; kt < 12; ++kt) {
        int krow = k0 + kt * 16 + l15;
        int kcl = krow < 0 ? 0 : (krow >= SDIM ? SDIM - 1 : krow);
        const f16x8* kp = (const f16x8*)(Kb + (long)kcl * HD + lg * 8);
        f16x8 kb0 = kp[0], kb1 = kp[4];
        f32x4 acc = {0.f, 0.f, 0.f, 0.f};
        acc = __builtin_amdgcn_mfma_f32_16x16x32_f16(qa0, kb0, acc, 0, 0, 0);
        acc = __builtin_amdgcn_mfma_f32_16x16x32_f16(qa1, kb1, acc, 0, 0, 0);
        int jk = kt * 16 + l15;
        bool kin = (krow >= 0) && (krow < SDIM);
#pragma unroll
        for (int j = 0; j < 4; ++j) {
            int i = iqb + j;
            bool valid = kin && (jk >= i) && (jk <= i + 128);
            float p = valid ? __expf(acc[j] * 0.125f) : 0.f;
            sums[j] += p;
            lsP[(w * 16 + lg * 4 + j) * PSTR + jk] = (_Float16)p;
        }
    }

#pragma unroll
    for (int m = 1; m < 16; m <<= 1) {
#pragma unroll
        for (int j = 0; j < 4; ++j)
            sums[j] += __shfl_xor(sums[j], m, 64);
    }
    float inv[4];
#pragma unroll
    for (int j = 0; j < 4; ++j) inv[j] = 1.f / sums[j];

    __syncthreads();

    f32x4 accy[4] = {};
    const _Float16* prow = &lsP[(w * 16 + l15) * PSTR + lg * 8];
#pragma unroll
    for (int kc = 0; kc < 6; ++kc) {
        f16x8 pa = *(const f16x8*)(prow + kc * 32);
#pragma unroll
        for (int dt = 0; dt < 4; ++dt) {
            f16x8 vb = *(const f16x8*)&lsVT[(dt * 16 + l15) * SSTR + kc * 32 + lg * 8];
            accy[dt] = __builtin_amdgcn_mfma_f32_16x16x32_f16(pa, vb, accy[dt], 0, 0, 0);
        }
    }

    int b = bh / NH, h = bh - (bh / NH) * NH;
    long outbase = ((long)b * SDIM) * HDIM + (long)h * HD;
#pragma unroll
    for (int dt = 0; dt < 4; ++dt) {
#pragma unroll
        for (int j = 0; j < 4; ++j) {
            int srow = q0 + w * 16 + lg * 4 + j;
            yh[outbase + (long)srow * HDIM + dt * 16 + l15] =
                (_Float16)(accy[dt][j] * inv[j]);
        }
    }
}

// ---------------------------------------------------------------------------
extern "C" void kernel_launch(void* const* d_in, const int* in_sizes, int n_in,
                              void* d_out, int out_size, void* d_ws, size_t ws_size,
                              hipStream_t stream)
{
    const float* x    = (const float*)d_in[0];
    const float* cosp = (const float*)d_in[1];
    const float* sinp = (const float*)d_in[2];
    const float* Wqkv = (const float*)d_in[3];
    const float* Wo   = (const float*)d_in[4];
    float* out = (float*)d_out;

    char* ws = (char*)d_ws;
    _Float16* wqkvh = (_Float16*)(ws);                    //  3,538,944
    _Float16* woh   = (_Float16*)(ws + 3538944);          //  1,179,648
    _Float16* qh    = (_Float16*)(ws + 4718592);          // 12,582,912
    _Float16* kh    = (_Float16*)(ws + 17301504);         // 12,582,912
    _Float16* vh    = (_Float16*)(ws + 29884416);         // 12,582,912
    _Float16* yh    = (_Float16*)(ws + 42467328);         // 12,582,912 -> 55,050,240 total

    // 1) convert weights to f16 (x conversion is fused into the QKV gemm)
    {
        int nthr = NQKV * HDIM / 8 + HDIM * HDIM / 8;   // 294912
        cvt_weights<<<(nthr + 255) / 256, 256, 0, stream>>>(Wqkv, Wo, wqkvh, woh);
    }

    // 2) QKV gemm: fused f32->f16 A-staging + RoPE + scatter epilogue
    {
        dim3 grid((MROWS / 128) * (NQKV / 128));   // 1152
        gemm_qkv<<<grid, 256, 0, stream>>>(x, wqkvh, cosp, sinp, qh, kh, vh);
    }

    // 3) sliding-window MFMA attention
    {
        dim3 grid(BDIM * NH * (SDIM / 64));        // 1536
        attn_mfma<<<grid, 256, 0, stream>>>(qh, kh, vh, yh);
    }

    // 4) output projection
    {
        dim3 grid((MROWS / 128) * (HDIM / 128));   // 384
        gemm_op<<<grid, 256, 0, stream>>>(yh, woh, out, MROWS, HDIM, HDIM);
    }
}

// Round 11
// 113.250 us; speedup vs baseline: 1.9521x; 1.0129x over previous
//
#include <hip/hip_runtime.h>

// ---------------------------------------------------------------------------
// ModernBertAttention: x[4,2048,768] -> QKV gemm(+RoPE) -> sliding-window
// MFMA attention (window=64) -> out-proj gemm.  out f32 [4,2048,768].
// ---------------------------------------------------------------------------

typedef __attribute__((ext_vector_type(8))) _Float16 f16x8;
typedef __attribute__((ext_vector_type(4))) float    f32x4;

#define BDIM 4
#define SDIM 2048
#define HDIM 768
#define NH   12
#define HD   64
#define NQKV 2304   // 3*HDIM
#define MROWS 8192  // B*S

#define MFMA16(a, b, c) __builtin_amdgcn_mfma_f32_16x16x32_f16(a, b, c, 0, 0, 0)

// ---------------------------------------------------------------------------
__device__ __forceinline__ void gload16(const void* g, void* l) {
    __builtin_amdgcn_global_load_lds(
        (__attribute__((address_space(1))) void*)(g),
        (__attribute__((address_space(3))) void*)(l),
        16, 0, 0);
}

// --------------------- f32 -> f16 convert (x + weights) ---------------------
__global__ __launch_bounds__(256) void cvt_all(
    const float* __restrict__ x,    _Float16* __restrict__ dx,
    const float* __restrict__ wqkv, _Float16* __restrict__ dq,
    const float* __restrict__ wo,   _Float16* __restrict__ dwo)
{
    const int n0 = MROWS * HDIM / 8;  // 786432
    const int n1 = NQKV * HDIM / 8;   // 221184
    const int n2 = HDIM * HDIM / 8;   //  73728
    int i = blockIdx.x * 256 + threadIdx.x;
    const float* s; _Float16* d; int j;
    if (i < n0)                 { s = x;    d = dx;  j = i; }
    else if (i < n0 + n1)       { s = wqkv; d = dq;  j = i - n0; }
    else if (i < n0 + n1 + n2)  { s = wo;   d = dwo; j = i - n0 - n1; }
    else return;
    const float4* s4 = (const float4*)s + (long)j * 2;
    float4 a = s4[0], b = s4[1];
    f16x8 o;
    o[0] = (_Float16)a.x; o[1] = (_Float16)a.y;
    o[2] = (_Float16)a.z; o[3] = (_Float16)a.w;
    o[4] = (_Float16)b.x; o[5] = (_Float16)b.y;
    o[6] = (_Float16)b.z; o[7] = (_Float16)b.w;
    *((f16x8*)d + j) = o;
}

// ---------------- QKV GEMM: triple-buffered counted-vmcnt -------------------
// C = xh[8192,768] * Wqkv^T[2304,768], tile 256x256, 8 waves (2Mx4N), BK=32.
// THE pipeline fix: 3 LDS buffers; during tile t stage tile t+2; at tile end
// wait vmcnt(4) (tile t+1 resident, t+2's 4 loads STAY IN FLIGHT across the
// barrier). One raw s_barrier per tile, no drain-to-0 -> ~2-tile (~1000 cyc)
// latency cover per load (m233/m218: the 2-phase drain was ~72% of crit path).
// LDS XOR-swizzle both-sides: phys_granule = logical ^ ((row>>1)&3) ->
// ds_read_b128 hits 8 distinct bank-quads per 16 lanes (2-way = free).
// Epilogue: RoPE q/k + scatter q/k/v (f16) to [B,nh,S,hd].
__global__ __launch_bounds__(512) void gemm_qkv8(
    const _Float16* __restrict__ A,     // xh
    const _Float16* __restrict__ Bt,    // wqkvh
    const float* __restrict__ cosp,
    const float* __restrict__ sinp,
    _Float16* __restrict__ qh,
    _Float16* __restrict__ kh,
    _Float16* __restrict__ vh)
{
    const int K = HDIM;
    __shared__ __align__(16) _Float16 lsA[3][256 * 32];   // 16KB each
    __shared__ __align__(16) _Float16 lsB[3][256 * 32];

    int nwg = gridDim.x;
    int bid = blockIdx.x;
    int cpx = nwg >> 3;                       // 288 % 8 == 0
    int wg  = (bid & 7) * cpx + (bid >> 3);   // XCD-aware bijective swizzle
    int tm = wg / 9, tn = wg % 9;
    int m0 = tm << 8, n0 = tn << 8;

    int tid  = threadIdx.x;
    int lane = tid & 63;
    int w    = tid >> 6;
    int wr   = w >> 2, wc = w & 3;            // wave grid 2M x 4N
    int l15  = lane & 15, lk = lane >> 4;

    f32x4 acc[8][4] = {};

    // staging: slot = tid + j*512 -> row slot>>2 (0..255 via j), phys gran slot&3
    int srow = tid >> 2;                      // 0..127
    int lg   = (tid & 3) ^ ((tid >> 3) & 3);  // pre-swizzled source granule
    const _Float16* gA = A  + (long)(m0 + srow) * K + lg * 8;
    const _Float16* gB = Bt + (long)(n0 + srow) * K + lg * 8;

    auto STAGE = [&](_Float16* ls, const _Float16* g, int t) {
        gload16(g + t * 32,             ls + tid * 8);
        gload16(g + t * 32 + 128L * K,  ls + tid * 8 + 4096);
    };
    auto RDA = [&](const _Float16* base, int mf) -> f16x8 {
        int r = wr * 128 + mf * 16 + l15;
        int pg = lk ^ ((r >> 1) & 3);
        return *(const f16x8*)&base[r * 32 + pg * 8];
    };
    auto RDB = [&](const _Float16* base, int nf) -> f16x8 {
        int r = wc * 64 + nf * 16 + l15;
        int pg = lk ^ ((r >> 1) & 3);
        return *(const f16x8*)&base[r * 32 + pg * 8];
    };

    const int NT = K >> 5;   // 24

    // prologue: tiles 0,1 in flight (8 loads); wait tile 0 (4 newest remain)
    STAGE(lsA[0], gA, 0); STAGE(lsB[0], gB, 0);
    STAGE(lsA[1], gA, 1); STAGE(lsB[1], gB, 1);
    asm volatile("s_waitcnt vmcnt(4)" ::: "memory");
    __builtin_amdgcn_s_barrier();

    int cur = 0;
    for (int t = 0; t < NT; ++t) {
        const _Float16* aC = lsA[cur];
        const _Float16* bC = lsB[cur];
        int stg = cur + 2; if (stg >= 3) stg -= 3;

        f16x8 af[4], bf[4];
#pragma unroll
        for (int mf = 0; mf < 4; ++mf) af[mf] = RDA(aC, mf);
#pragma unroll
        for (int nf = 0; nf < 4; ++nf) bf[nf] = RDB(bC, nf);
        if (t + 2 < NT) STAGE(lsA[stg], gA, t + 2);

        __builtin_amdgcn_s_setprio(1);
#pragma unroll
        for (int mf = 0; mf < 4; ++mf)
#pragma unroll
            for (int nf = 0; nf < 4; ++nf)
                acc[mf][nf] = MFMA16(af[mf], bf[nf], acc[mf][nf]);
        __builtin_amdgcn_s_setprio(0);

#pragma unroll
        for (int mf = 0; mf < 4; ++mf) af[mf] = RDA(aC, 4 + mf);
        if (t + 2 < NT) STAGE(lsB[stg], gB, t + 2);

        __builtin_amdgcn_s_setprio(1);
#pragma unroll
        for (int mf = 0; mf < 4; ++mf)
#pragma unroll
            for (int nf = 0; nf < 4; ++nf)
                acc[4 + mf][nf] = MFMA16(af[mf], bf[nf], acc[4 + mf][nf]);
        __builtin_amdgcn_s_setprio(0);

        if (t + 1 < NT) {
            if (t + 2 < NT)
                asm volatile("s_waitcnt vmcnt(4)" ::: "memory"); // t+1 resident, t+2 in flight
            else
                asm volatile("s_waitcnt vmcnt(0)" ::: "memory");
            __builtin_amdgcn_s_barrier();
        }
        cur = cur + 1; if (cur == 3) cur = 0;
    }

    // ---- epilogue: RoPE + scatter ----
    int ht = (n0 >> 6) + wc;       // [0,36): t*12 + h
    int tq = ht / NH;
    int h  = ht - tq * NH;
    int b  = m0 >> 11;             // 256-row tile never straddles a batch
    long base_bh = ((long)(b * NH + h)) * SDIM;
#pragma unroll
    for (int mf = 0; mf < 8; ++mf) {
#pragma unroll
        for (int j = 0; j < 4; ++j) {
            int gr = m0 + wr * 128 + mf * 16 + lk * 4 + j;
            int s  = gr & (SDIM - 1);
            if (tq == 2) {
#pragma unroll
                for (int nf = 0; nf < 4; ++nf) {
                    int d = nf * 16 + l15;
                    vh[(base_bh + s) * HD + d] = (_Float16)acc[mf][nf][j];
                }
            } else {
                float vals[4];
#pragma unroll
                for (int nf = 0; nf < 4; ++nf) vals[nf] = acc[mf][nf][j];
#pragma unroll
                for (int nf = 0; nf < 4; ++nf) {
                    int d = nf * 16 + l15;
                    float cc = cosp[(long)gr * HD + d];
                    float ss = sinp[(long)gr * HD + d];
                    float pv = (nf < 2) ? -vals[nf + 2] : vals[nf - 2];
                    float o  = vals[nf] * cc + pv * ss;
                    long oidx = (base_bh + s) * HD + d;
                    if (tq == 0) qh[oidx] = (_Float16)o;
                    else         kh[oidx] = (_Float16)o;
                }
            }
        }
    }
}

// --------------- out-proj GEMM: same pipeline at 128x128 --------------------
// 4 waves (2x2), BK=32, triple-buffered (48KB -> 3 blocks/CU), grid 384.
__global__ __launch_bounds__(256) void gemm_op8(
    const _Float16* __restrict__ A,
    const _Float16* __restrict__ Bt,
    float* __restrict__ C,
    int M, int N, int K)
{
    __shared__ __align__(16) _Float16 lsA[3][128 * 32];   // 8KB each
    __shared__ __align__(16) _Float16 lsB[3][128 * 32];

    int nTn = N >> 7;
    int nwg = gridDim.x;
    int bid = blockIdx.x;
    int cpx = nwg >> 3;
    int wg  = (bid & 7) * cpx + (bid >> 3);
    int tm = wg / nTn, tn = wg % nTn;
    int m0 = tm << 7, n0 = tn << 7;

    int tid  = threadIdx.x;
    int lane = tid & 63;
    int w    = tid >> 6;
    int wr   = w >> 1, wc = w & 1;
    int l15  = lane & 15, lk = lane >> 4;

    f32x4 acc[4][4] = {};

    int srow = tid >> 2;                      // 0..63
    int lg   = (tid & 3) ^ ((tid >> 3) & 3);
    const _Float16* gA = A  + (long)(m0 + srow) * K + lg * 8;
    const _Float16* gB = Bt + (long)(n0 + srow) * K + lg * 8;

    auto STAGE = [&](_Float16* ls, const _Float16* g, int t) {
        gload16(g + t * 32,            ls + tid * 8);
        gload16(g + t * 32 + 64L * K,  ls + tid * 8 + 2048);
    };
    auto RD = [&](const _Float16* base, int rbase, int f) -> f16x8 {
        int r = rbase + f * 16 + l15;
        int pg = lk ^ ((r >> 1) & 3);
        return *(const f16x8*)&base[r * 32 + pg * 8];
    };

    const int NT = K >> 5;   // 24

    STAGE(lsA[0], gA, 0); STAGE(lsB[0], gB, 0);
    STAGE(lsA[1], gA, 1); STAGE(lsB[1], gB, 1);
    asm volatile("s_waitcnt vmcnt(4)" ::: "memory");
    __builtin_amdgcn_s_barrier();

    int cur = 0;
    for (int t = 0; t < NT; ++t) {
        const _Float16* aC = lsA[cur];
        const _Float16* bC = lsB[cur];
        int stg = cur + 2; if (stg >= 3) stg -= 3;

        f16x8 af[4], bf[4];
#pragma unroll
        for (int mf = 0; mf < 4; ++mf) af[mf] = RD(aC, wr * 64, mf);
#pragma unroll
        for (int nf = 0; nf < 4; ++nf) bf[nf] = RD(bC, wc * 64, nf);
        if (t + 2 < NT) { STAGE(lsA[stg], gA, t + 2); STAGE(lsB[stg], gB, t + 2); }

        __builtin_amdgcn_s_setprio(1);
#pragma unroll
        for (int mf = 0; mf < 4; ++mf)
#pragma unroll
            for (int nf = 0; nf < 4; ++nf)
                acc[mf][nf] = MFMA16(af[mf], bf[nf], acc[mf][nf]);
        __builtin_amdgcn_s_setprio(0);

        if (t + 1 < NT) {
            if (t + 2 < NT)
                asm volatile("s_waitcnt vmcnt(4)" ::: "memory");
            else
                asm volatile("s_waitcnt vmcnt(0)" ::: "memory");
            __builtin_amdgcn_s_barrier();
        }
        cur = cur + 1; if (cur == 3) cur = 0;
    }

#pragma unroll
    for (int mf = 0; mf < 4; ++mf)
#pragma unroll
        for (int nf = 0; nf < 4; ++nf)
#pragma unroll
            for (int j = 0; j < 4; ++j) {
                int gr = m0 + wr * 64 + mf * 16 + lk * 4 + j;
                int gc = n0 + wc * 64 + nf * 16 + l15;
                C[(long)gr * N + gc] = acc[mf][nf][j];
            }
}

// ---------------------------- MFMA attention --------------------------------
// Block = 4 waves = one (b,h, 64-query tile); key window = 192 keys.
#define SSTR 200
#define PSTR 200
__global__ __launch_bounds__(256) void attn_mfma(
    const _Float16* __restrict__ qh,
    const _Float16* __restrict__ kh,
    const _Float16* __restrict__ vh,
    _Float16* __restrict__ yh)
{
    __shared__ __align__(16) _Float16 lsVT[64 * SSTR];
    __shared__ __align__(16) _Float16 lsP [64 * PSTR];

    int bid = blockIdx.x;
    int qt  = bid & 31;
    int bh  = bid >> 5;
    int q0  = qt << 6;
    int k0  = q0 - 64;
    int tid = threadIdx.x;
    int lane = tid & 63;
    int w = tid >> 6;
    int l15 = lane & 15, lg = lane >> 4;

    const _Float16* Qb = qh + (long)bh * SDIM * HD;
    const _Float16* Kb = kh + (long)bh * SDIM * HD;
    const _Float16* Vb = vh + (long)bh * SDIM * HD;

#pragma unroll
    for (int c = 0; c < 3; ++c) {
        int rk = c * 64 + lane;
        int s  = k0 + rk;
        s = s < 0 ? 0 : (s >= SDIM ? SDIM - 1 : s);
        const f16x8* vr = (const f16x8*)(Vb + (long)s * HD + w * 16);
        f16x8 v0 = vr[0], v1 = vr[1];
#pragma unroll
        for (int e = 0; e < 8; ++e) {
            lsVT[(w * 16 + e)     * SSTR + rk] = v0[e];
            lsVT[(w * 16 + 8 + e) * SSTR + rk] = v1[e];
        }
    }

    int qrow = q0 + w * 16 + l15;
    const f16x8* qp = (const f16x8*)(Qb + (long)qrow * HD + lg * 8);
    f16x8 qa0 = qp[0];
    f16x8 qa1 = qp[4];

    float sums[4] = {0.f, 0.f, 0.f, 0.f};
    int iqb = w * 16 + lg * 4;
#pragma unroll 4
    for (int kt = 0; kt < 12; ++kt) {
        int krow = k0 + kt * 16 + l15;
        int kcl = krow < 0 ? 0 : (krow >= SDIM ? SDIM - 1 : krow);
        const f16x8* kp = (const f16x8*)(Kb + (long)kcl * HD + lg * 8);
        f16x8 kb0 = kp[0], kb1 = kp[4];
        f32x4 acc = {0.f, 0.f, 0.f, 0.f};
        acc = MFMA16(qa0, kb0, acc);
        acc = MFMA16(qa1, kb1, acc);
        int jk = kt * 16 + l15;
        bool kin = (krow >= 0) && (krow < SDIM);
#pragma unroll
        for (int j = 0; j < 4; ++j) {
            int i = iqb + j;
            bool valid = kin && (jk >= i) && (jk <= i + 128);
            float p = valid ? __expf(acc[j] * 0.125f) : 0.f;
            sums[j] += p;
            lsP[(w * 16 + lg * 4 + j) * PSTR + jk] = (_Float16)p;
        }
    }

#pragma unroll
    for (int m = 1; m < 16; m <<= 1) {
#pragma unroll
        for (int j = 0; j < 4; ++j)
            sums[j] += __shfl_xor(sums[j], m, 64);
    }
    float inv[4];
#pragma unroll
    for (int j = 0; j < 4; ++j) inv[j] = 1.f / sums[j];

    __syncthreads();

    f32x4 accy[4] = {};
    const _Float16* prow = &lsP[(w * 16 + l15) * PSTR + lg * 8];
#pragma unroll
    for (int kc = 0; kc < 6; ++kc) {
        f16x8 pa = *(const f16x8*)(prow + kc * 32);
#pragma unroll
        for (int dt = 0; dt < 4; ++dt) {
            f16x8 vb = *(const f16x8*)&lsVT[(dt * 16 + l15) * SSTR + kc * 32 + lg * 8];
            accy[dt] = MFMA16(pa, vb, accy[dt]);
        }
    }

    int b = bh / NH, h = bh - (bh / NH) * NH;
    long outbase = ((long)b * SDIM) * HDIM + (long)h * HD;
#pragma unroll
    for (int dt = 0; dt < 4; ++dt) {
#pragma unroll
        for (int j = 0; j < 4; ++j) {
            int srow = q0 + w * 16 + lg * 4 + j;
            yh[outbase + (long)srow * HDIM + dt * 16 + l15] =
                (_Float16)(accy[dt][j] * inv[j]);
        }
    }
}

// ---------------------------------------------------------------------------
extern "C" void kernel_launch(void* const* d_in, const int* in_sizes, int n_in,
                              void* d_out, int out_size, void* d_ws, size_t ws_size,
                              hipStream_t stream)
{
    const float* x    = (const float*)d_in[0];
    const float* cosp = (const float*)d_in[1];
    const float* sinp = (const float*)d_in[2];
    const float* Wqkv = (const float*)d_in[3];
    const float* Wo   = (const float*)d_in[4];
    float* out = (float*)d_out;

    char* ws = (char*)d_ws;
    _Float16* xh    = (_Float16*)(ws);                    // 12,582,912
    _Float16* wqkvh = (_Float16*)(ws + 12582912);         //  3,538,944
    _Float16* woh   = (_Float16*)(ws + 16121856);         //  1,179,648
    _Float16* qh    = (_Float16*)(ws + 17301504);         // 12,582,912
    _Float16* kh    = (_Float16*)(ws + 29884416);         // 12,582,912
    _Float16* vh    = (_Float16*)(ws + 42467328);         // 12,582,912
    _Float16* yh    = (_Float16*)(ws + 55050240);         // 12,582,912 -> 67,633,152

    // 1) convert x + weights to f16 (single kernel)
    {
        int nthr = MROWS * HDIM / 8 + NQKV * HDIM / 8 + HDIM * HDIM / 8;
        cvt_all<<<(nthr + 255) / 256, 256, 0, stream>>>(x, xh, Wqkv, wqkvh, Wo, woh);
    }

    // 2) QKV gemm: 256x256, triple-buffered counted-vmcnt, fused RoPE+scatter
    {
        dim3 grid((MROWS / 256) * (NQKV / 256));   // 32*9 = 288
        gemm_qkv8<<<grid, 512, 0, stream>>>(xh, wqkvh, cosp, sinp, qh, kh, vh);
    }

    // 3) sliding-window MFMA attention
    {
        dim3 grid(BDIM * NH * (SDIM / 64));        // 1536
        attn_mfma<<<grid, 256, 0, stream>>>(qh, kh, vh, yh);
    }

    // 4) output projection: 128x128, triple-buffered counted-vmcnt
    {
        dim3 grid((MROWS / 128) * (HDIM / 128));   // 384
        gemm_op8<<<grid, 256, 0, stream>>>(yh, woh, out, MROWS, HDIM, HDIM);
    }
}

// Round 12
// 106.248 us; speedup vs baseline: 2.0808x; 1.0659x over previous
//
#include <hip/hip_runtime.h>

// ---------------------------------------------------------------------------
// ModernBertAttention: x[4,2048,768] -> QKV gemm(+RoPE) -> sliding-window
// MFMA attention (window=64) -> out-proj gemm.  out f32 [4,2048,768].
// ---------------------------------------------------------------------------

typedef __attribute__((ext_vector_type(8))) _Float16 f16x8;
typedef __attribute__((ext_vector_type(4))) float    f32x4;

#define BDIM 4
#define SDIM 2048
#define HDIM 768
#define NH   12
#define HD   64
#define NQKV 2304   // 3*HDIM
#define MROWS 8192  // B*S

#define MFMA16(a, b, c) __builtin_amdgcn_mfma_f32_16x16x32_f16(a, b, c, 0, 0, 0)

// ---------------------------------------------------------------------------
__device__ __forceinline__ void gload16(const void* g, void* l) {
    __builtin_amdgcn_global_load_lds(
        (__attribute__((address_space(1))) void*)(g),
        (__attribute__((address_space(3))) void*)(l),
        16, 0, 0);
}

// --------------------- f32 -> f16 convert (x + weights) ---------------------
__global__ __launch_bounds__(256) void cvt_all(
    const float* __restrict__ x,    _Float16* __restrict__ dx,
    const float* __restrict__ wqkv, _Float16* __restrict__ dq,
    const float* __restrict__ wo,   _Float16* __restrict__ dwo)
{
    const int n0 = MROWS * HDIM / 8;  // 786432
    const int n1 = NQKV * HDIM / 8;   // 221184
    const int n2 = HDIM * HDIM / 8;   //  73728
    int i = blockIdx.x * 256 + threadIdx.x;
    const float* s; _Float16* d; int j;
    if (i < n0)                 { s = x;    d = dx;  j = i; }
    else if (i < n0 + n1)       { s = wqkv; d = dq;  j = i - n0; }
    else if (i < n0 + n1 + n2)  { s = wo;   d = dwo; j = i - n0 - n1; }
    else return;
    const float4* s4 = (const float4*)s + (long)j * 2;
    float4 a = s4[0], b = s4[1];
    f16x8 o;
    o[0] = (_Float16)a.x; o[1] = (_Float16)a.y;
    o[2] = (_Float16)a.z; o[3] = (_Float16)a.w;
    o[4] = (_Float16)b.x; o[5] = (_Float16)b.y;
    o[6] = (_Float16)b.z; o[7] = (_Float16)b.w;
    *((f16x8*)d + j) = o;
}

// ------------- QKV GEMM: 128x128 triple-buffered counted-vmcnt --------------
// R11 engine (triple LDS buffer, stage t+2 during t, vmcnt(4) at tile end --
// never drain to 0 in steady state, one raw s_barrier/tile) at the R5 tile
// geometry: 128x128, 4 waves, BK=32 -> 48KB LDS = 3 blocks/CU = 12 waves/CU
// (3/SIMD for stall coverage), grid 1152 (4.5 blocks/CU, smooth tail).
// LDS XOR-swizzle both-sides: phys_granule = logical ^ ((row>>1)&3).
// Epilogue: RoPE q/k + scatter q/k/v (f16) to [B,nh,S,hd].
__global__ __launch_bounds__(256) void gemm_qkv_t3(
    const _Float16* __restrict__ A,     // xh
    const _Float16* __restrict__ Bt,    // wqkvh
    const float* __restrict__ cosp,
    const float* __restrict__ sinp,
    _Float16* __restrict__ qh,
    _Float16* __restrict__ kh,
    _Float16* __restrict__ vh)
{
    const int K = HDIM;
    __shared__ __align__(16) _Float16 lsA[3][128 * 32];   // 8KB each
    __shared__ __align__(16) _Float16 lsB[3][128 * 32];

    const int nTn = NQKV >> 7;                // 18
    int nwg = gridDim.x;
    int bid = blockIdx.x;
    int cpx = nwg >> 3;                       // 1152 % 8 == 0
    int wg  = (bid & 7) * cpx + (bid >> 3);   // XCD-aware bijective swizzle
    int tm = wg / nTn, tn = wg % nTn;
    int m0 = tm << 7, n0 = tn << 7;

    int tid  = threadIdx.x;
    int lane = tid & 63;
    int w    = tid >> 6;
    int wr   = w >> 1, wc = w & 1;
    int l15  = lane & 15, lk = lane >> 4;

    f32x4 acc[4][4] = {};

    int srow = tid >> 2;                      // 0..63
    int lg   = (tid & 3) ^ ((tid >> 3) & 3);  // pre-swizzled source granule
    const _Float16* gA = A  + (long)(m0 + srow) * K + lg * 8;
    const _Float16* gB = Bt + (long)(n0 + srow) * K + lg * 8;

    auto STAGE = [&](int buf, int t) {
        gload16(gA + t * 32,            &lsA[buf][tid * 8]);
        gload16(gA + t * 32 + 64L * K,  &lsA[buf][tid * 8 + 2048]);
        gload16(gB + t * 32,            &lsB[buf][tid * 8]);
        gload16(gB + t * 32 + 64L * K,  &lsB[buf][tid * 8 + 2048]);
    };
    auto RD = [&](const _Float16* base, int rbase, int f) -> f16x8 {
        int r = rbase + f * 16 + l15;
        int pg = lk ^ ((r >> 1) & 3);
        return *(const f16x8*)&base[r * 32 + pg * 8];
    };

    const int NT = K >> 5;   // 24

    STAGE(0, 0);
    STAGE(1, 1);
    asm volatile("s_waitcnt vmcnt(4)" ::: "memory");   // tile 0 resident
    __builtin_amdgcn_s_barrier();

    int cur = 0;
    for (int t = 0; t < NT; ++t) {
        const _Float16* aC = lsA[cur];
        const _Float16* bC = lsB[cur];
        int stg = cur + 2; if (stg >= 3) stg -= 3;

        f16x8 af[4], bf[4];
#pragma unroll
        for (int mf = 0; mf < 4; ++mf) af[mf] = RD(aC, wr * 64, mf);
#pragma unroll
        for (int nf = 0; nf < 4; ++nf) bf[nf] = RD(bC, wc * 64, nf);
        if (t + 2 < NT) STAGE(stg, t + 2);

        __builtin_amdgcn_s_setprio(1);
#pragma unroll
        for (int mf = 0; mf < 4; ++mf)
#pragma unroll
            for (int nf = 0; nf < 4; ++nf)
                acc[mf][nf] = MFMA16(af[mf], bf[nf], acc[mf][nf]);
        __builtin_amdgcn_s_setprio(0);

        if (t + 1 < NT) {
            if (t + 2 < NT)
                asm volatile("s_waitcnt vmcnt(4)" ::: "memory"); // t+1 resident, t+2 in flight
            else
                asm volatile("s_waitcnt vmcnt(0)" ::: "memory");
            __builtin_amdgcn_s_barrier();
        }
        cur = cur + 1; if (cur == 3) cur = 0;
    }

    // ---- epilogue: RoPE + scatter ----
    int ht = (n0 >> 6) + wc;       // [0,36): t*12 + h
    int tq = ht / NH;
    int h  = ht - tq * NH;
    int b  = m0 >> 11;
    long base_bh = ((long)(b * NH + h)) * SDIM;
#pragma unroll
    for (int mf = 0; mf < 4; ++mf) {
#pragma unroll
        for (int j = 0; j < 4; ++j) {
            int gr = m0 + wr * 64 + mf * 16 + lk * 4 + j;
            int s  = gr & (SDIM - 1);
            if (tq == 2) {
#pragma unroll
                for (int nf = 0; nf < 4; ++nf) {
                    int d = nf * 16 + l15;
                    vh[(base_bh + s) * HD + d] = (_Float16)acc[mf][nf][j];
                }
            } else {
                float vals[4];
#pragma unroll
                for (int nf = 0; nf < 4; ++nf) vals[nf] = acc[mf][nf][j];
#pragma unroll
                for (int nf = 0; nf < 4; ++nf) {
                    int d = nf * 16 + l15;
                    float cc = cosp[(long)gr * HD + d];
                    float ss = sinp[(long)gr * HD + d];
                    float pv = (nf < 2) ? -vals[nf + 2] : vals[nf - 2];
                    float o  = vals[nf] * cc + pv * ss;
                    long oidx = (base_bh + s) * HD + d;
                    if (tq == 0) qh[oidx] = (_Float16)o;
                    else         kh[oidx] = (_Float16)o;
                }
            }
        }
    }
}

// --------------- out-proj GEMM: same pipeline at 128x128 --------------------
// (unchanged from R11 -- verified)
__global__ __launch_bounds__(256) void gemm_op8(
    const _Float16* __restrict__ A,
    const _Float16* __restrict__ Bt,
    float* __restrict__ C,
    int M, int N, int K)
{
    __shared__ __align__(16) _Float16 lsA[3][128 * 32];
    __shared__ __align__(16) _Float16 lsB[3][128 * 32];

    int nTn = N >> 7;
    int nwg = gridDim.x;
    int bid = blockIdx.x;
    int cpx = nwg >> 3;
    int wg  = (bid & 7) * cpx + (bid >> 3);
    int tm = wg / nTn, tn = wg % nTn;
    int m0 = tm << 7, n0 = tn << 7;

    int tid  = threadIdx.x;
    int lane = tid & 63;
    int w    = tid >> 6;
    int wr   = w >> 1, wc = w & 1;
    int l15  = lane & 15, lk = lane >> 4;

    f32x4 acc[4][4] = {};

    int srow = tid >> 2;
    int lg   = (tid & 3) ^ ((tid >> 3) & 3);
    const _Float16* gA = A  + (long)(m0 + srow) * K + lg * 8;
    const _Float16* gB = Bt + (long)(n0 + srow) * K + lg * 8;

    auto STAGE = [&](int buf, int t) {
        gload16(gA + t * 32,            &lsA[buf][tid * 8]);
        gload16(gA + t * 32 + 64L * K,  &lsA[buf][tid * 8 + 2048]);
        gload16(gB + t * 32,            &lsB[buf][tid * 8]);
        gload16(gB + t * 32 + 64L * K,  &lsB[buf][tid * 8 + 2048]);
    };
    auto RD = [&](const _Float16* base, int rbase, int f) -> f16x8 {
        int r = rbase + f * 16 + l15;
        int pg = lk ^ ((r >> 1) & 3);
        return *(const f16x8*)&base[r * 32 + pg * 8];
    };

    const int NT = K >> 5;   // 24

    STAGE(0, 0);
    STAGE(1, 1);
    asm volatile("s_waitcnt vmcnt(4)" ::: "memory");
    __builtin_amdgcn_s_barrier();

    int cur = 0;
    for (int t = 0; t < NT; ++t) {
        const _Float16* aC = lsA[cur];
        const _Float16* bC = lsB[cur];
        int stg = cur + 2; if (stg >= 3) stg -= 3;

        f16x8 af[4], bf[4];
#pragma unroll
        for (int mf = 0; mf < 4; ++mf) af[mf] = RD(aC, wr * 64, mf);
#pragma unroll
        for (int nf = 0; nf < 4; ++nf) bf[nf] = RD(bC, wc * 64, nf);
        if (t + 2 < NT) STAGE(stg, t + 2);

        __builtin_amdgcn_s_setprio(1);
#pragma unroll
        for (int mf = 0; mf < 4; ++mf)
#pragma unroll
            for (int nf = 0; nf < 4; ++nf)
                acc[mf][nf] = MFMA16(af[mf], bf[nf], acc[mf][nf]);
        __builtin_amdgcn_s_setprio(0);

        if (t + 1 < NT) {
            if (t + 2 < NT)
                asm volatile("s_waitcnt vmcnt(4)" ::: "memory");
            else
                asm volatile("s_waitcnt vmcnt(0)" ::: "memory");
            __builtin_amdgcn_s_barrier();
        }
        cur = cur + 1; if (cur == 3) cur = 0;
    }

#pragma unroll
    for (int mf = 0; mf < 4; ++mf)
#pragma unroll
        for (int nf = 0; nf < 4; ++nf)
#pragma unroll
            for (int j = 0; j < 4; ++j) {
                int gr = m0 + wr * 64 + mf * 16 + lk * 4 + j;
                int gc = n0 + wc * 64 + nf * 16 + l15;
                C[(long)gr * N + gc] = acc[mf][nf][j];
            }
}

// ---------------------------- MFMA attention --------------------------------
// Block = 4 waves = one (b,h, 64-query tile); key window = 192 keys.
#define SSTR 200
#define PSTR 200
__global__ __launch_bounds__(256) void attn_mfma(
    const _Float16* __restrict__ qh,
    const _Float16* __restrict__ kh,
    const _Float16* __restrict__ vh,
    _Float16* __restrict__ yh)
{
    __shared__ __align__(16) _Float16 lsVT[64 * SSTR];
    __shared__ __align__(16) _Float16 lsP [64 * PSTR];

    int bid = blockIdx.x;
    int qt  = bid & 31;
    int bh  = bid >> 5;
    int q0  = qt << 6;
    int k0  = q0 - 64;
    int tid = threadIdx.x;
    int lane = tid & 63;
    int w = tid >> 6;
    int l15 = lane & 15, lg = lane >> 4;

    const _Float16* Qb = qh + (long)bh * SDIM * HD;
    const _Float16* Kb = kh + (long)bh * SDIM * HD;
    const _Float16* Vb = vh + (long)bh * SDIM * HD;

#pragma unroll
    for (int c = 0; c < 3; ++c) {
        int rk = c * 64 + lane;
        int s  = k0 + rk;
        s = s < 0 ? 0 : (s >= SDIM ? SDIM - 1 : s);
        const f16x8* vr = (const f16x8*)(Vb + (long)s * HD + w * 16);
        f16x8 v0 = vr[0], v1 = vr[1];
#pragma unroll
        for (int e = 0; e < 8; ++e) {
            lsVT[(w * 16 + e)     * SSTR + rk] = v0[e];
            lsVT[(w * 16 + 8 + e) * SSTR + rk] = v1[e];
        }
    }

    int qrow = q0 + w * 16 + l15;
    const f16x8* qp = (const f16x8*)(Qb + (long)qrow * HD + lg * 8);
    f16x8 qa0 = qp[0];
    f16x8 qa1 = qp[4];

    float sums[4] = {0.f, 0.f, 0.f, 0.f};
    int iqb = w * 16 + lg * 4;
#pragma unroll 4
    for (int kt = 0; kt < 12; ++kt) {
        int krow = k0 + kt * 16 + l15;
        int kcl = krow < 0 ? 0 : (krow >= SDIM ? SDIM - 1 : krow);
        const f16x8* kp = (const f16x8*)(Kb + (long)kcl * HD + lg * 8);
        f16x8 kb0 = kp[0], kb1 = kp[4];
        f32x4 acc = {0.f, 0.f, 0.f, 0.f};
        acc = MFMA16(qa0, kb0, acc);
        acc = MFMA16(qa1, kb1, acc);
        int jk = kt * 16 + l15;
        bool kin = (krow >= 0) && (krow < SDIM);
#pragma unroll
        for (int j = 0; j < 4; ++j) {
            int i = iqb + j;
            bool valid = kin && (jk >= i) && (jk <= i + 128);
            float p = valid ? __expf(acc[j] * 0.125f) : 0.f;
            sums[j] += p;
            lsP[(w * 16 + lg * 4 + j) * PSTR + jk] = (_Float16)p;
        }
    }

#pragma unroll
    for (int m = 1; m < 16; m <<= 1) {
#pragma unroll
        for (int j = 0; j < 4; ++j)
            sums[j] += __shfl_xor(sums[j], m, 64);
    }
    float inv[4];
#pragma unroll
    for (int j = 0; j < 4; ++j) inv[j] = 1.f / sums[j];

    __syncthreads();

    f32x4 accy[4] = {};
    const _Float16* prow = &lsP[(w * 16 + l15) * PSTR + lg * 8];
#pragma unroll
    for (int kc = 0; kc < 6; ++kc) {
        f16x8 pa = *(const f16x8*)(prow + kc * 32);
#pragma unroll
        for (int dt = 0; dt < 4; ++dt) {
            f16x8 vb = *(const f16x8*)&lsVT[(dt * 16 + l15) * SSTR + kc * 32 + lg * 8];
            accy[dt] = MFMA16(pa, vb, accy[dt]);
        }
    }

    int b = bh / NH, h = bh - (bh / NH) * NH;
    long outbase = ((long)b * SDIM) * HDIM + (long)h * HD;
#pragma unroll
    for (int dt = 0; dt < 4; ++dt) {
#pragma unroll
        for (int j = 0; j < 4; ++j) {
            int srow = q0 + w * 16 + lg * 4 + j;
            yh[outbase + (long)srow * HDIM + dt * 16 + l15] =
                (_Float16)(accy[dt][j] * inv[j]);
        }
    }
}

// ---------------------------------------------------------------------------
extern "C" void kernel_launch(void* const* d_in, const int* in_sizes, int n_in,
                              void* d_out, int out_size, void* d_ws, size_t ws_size,
                              hipStream_t stream)
{
    const float* x    = (const float*)d_in[0];
    const float* cosp = (const float*)d_in[1];
    const float* sinp = (const float*)d_in[2];
    const float* Wqkv = (const float*)d_in[3];
    const float* Wo   = (const float*)d_in[4];
    float* out = (float*)d_out;

    char* ws = (char*)d_ws;
    _Float16* xh    = (_Float16*)(ws);                    // 12,582,912
    _Float16* wqkvh = (_Float16*)(ws + 12582912);         //  3,538,944
    _Float16* woh   = (_Float16*)(ws + 16121856);         //  1,179,648
    _Float16* qh    = (_Float16*)(ws + 17301504);         // 12,582,912
    _Float16* kh    = (_Float16*)(ws + 29884416);         // 12,582,912
    _Float16* vh    = (_Float16*)(ws + 42467328);         // 12,582,912
    _Float16* yh    = (_Float16*)(ws + 55050240);         // 12,582,912 -> 67,633,152

    // 1) convert x + weights to f16 (single kernel)
    {
        int nthr = MROWS * HDIM / 8 + NQKV * HDIM / 8 + HDIM * HDIM / 8;
        cvt_all<<<(nthr + 255) / 256, 256, 0, stream>>>(x, xh, Wqkv, wqkvh, Wo, woh);
    }

    // 2) QKV gemm: 128x128 triple-buffered counted-vmcnt, fused RoPE+scatter
    {
        dim3 grid((MROWS / 128) * (NQKV / 128));   // 1152: 4.5 blk/CU, smooth
        gemm_qkv_t3<<<grid, 256, 0, stream>>>(xh, wqkvh, cosp, sinp, qh, kh, vh);
    }

    // 3) sliding-window MFMA attention
    {
        dim3 grid(BDIM * NH * (SDIM / 64));        // 1536
        attn_mfma<<<grid, 256, 0, stream>>>(qh, kh, vh, yh);
    }

    // 4) output projection: 128x128, triple-buffered counted-vmcnt
    {
        dim3 grid((MROWS / 128) * (HDIM / 128));   // 384
        gemm_op8<<<grid, 256, 0, stream>>>(yh, woh, out, MROWS, HDIM, HDIM);
    }
}